// Round 3
// baseline (331.408 us; speedup 1.0000x reference)
//
#include <hip/hip_runtime.h>

// GaussianKernel: out[b,n,m] = exp(inv2s * (||Q[b,n]||^2 + ||KV[b,:,m]||^2 - 2*Q[b,n]·KV[b,:,m]))
// B=16, N=2048, M=2048, D=128, fp32 in/out.
//
// R2: merged prep launch, XCD-rect block swizzle (L2 footprint 576->384KB/XCD/batch),
//     exp2f epilogue (fold log2e), non-temporal full-line output stores.

#define B_  16
#define N_  2048
#define M_  2048
#define D_  128

typedef _Float16 half8 __attribute__((ext_vector_type(8)));
typedef float    f32x4 __attribute__((ext_vector_type(4)));

// ----------------------------------------------------------------- prep -----
// blocks [0, 8192): Q rows -> fp16 + row-sq (one wave per row).
// blocks [8192, 8320): KV -> KTh[b,m,k] fp16 transpose + col-sq.
__global__ __launch_bounds__(256) void prep(const float* __restrict__ Q,
                                            const float* __restrict__ KV,
                                            _Float16* __restrict__ Qh,
                                            _Float16* __restrict__ KTh,
                                            float* __restrict__ Qsq,
                                            float* __restrict__ Ksq) {
    if (blockIdx.x < 8192) {
        const int row  = blockIdx.x * 4 + (threadIdx.x >> 6);
        const int lane = threadIdx.x & 63;
        const float2 v = reinterpret_cast<const float2*>(Q + (size_t)row * D_)[lane];
        float sq = v.x * v.x + v.y * v.y;
        union { _Float16 h[2]; unsigned int u; } pk;
        pk.h[0] = (_Float16)v.x;
        pk.h[1] = (_Float16)v.y;
        reinterpret_cast<unsigned int*>(Qh + (size_t)row * D_)[lane] = pk.u;
        #pragma unroll
        for (int off = 32; off > 0; off >>= 1) sq += __shfl_down(sq, off, 64);
        if (lane == 0) Qsq[row] = sq;
    } else {
        const int bid = blockIdx.x - 8192;          // 0..127
        const int b   = bid >> 3;
        const int m   = (bid & 7) * 256 + threadIdx.x;
        const float* src = KV + (size_t)b * D_ * M_ + m;
        _Float16*   dst = KTh + ((size_t)b * M_ + m) * D_;
        float sq = 0.f;
        #pragma unroll 2
        for (int k0 = 0; k0 < D_; k0 += 8) {
            union { _Float16 h[8]; int4 v; } buf;
            #pragma unroll
            for (int j = 0; j < 8; ++j) {
                const float v = src[(size_t)(k0 + j) * M_];
                sq += v * v;
                buf.h[j] = (_Float16)v;
            }
            *reinterpret_cast<int4*>(dst + k0) = buf.v;
        }
        Ksq[(size_t)b * M_ + m] = sq;
    }
}

// ------------------------------------------------------------------ GEMM ----
// 128x128 tile per block, 4 waves (2x2 of 64x64), full K=128 staged once.
__global__ __launch_bounds__(256, 2) void gauss_gemm(
    const _Float16* __restrict__ Qh, const _Float16* __restrict__ KTh,
    const float* __restrict__ Qsq,  const float* __restrict__ Ksq,
    const float* __restrict__ ls,   float* __restrict__ out) {
    __shared__ __align__(16) char smem[132 * 128 * 4];   // 67584 B -> 2 blocks/CU
    _Float16* Ash = (_Float16*)smem;
    _Float16* Bsh = (_Float16*)(smem + 32768);

    const int b    = blockIdx.y;
    const int bx   = blockIdx.x;
    // XCD-rect swizzle: XCD = bx&7 (round-robin dispatch, grid.x=256 ≡ 0 mod 8).
    // Each XCD owns a 4(n) x 8(m) tile rect per batch: unique A 4 + B 8 tiles.
    const int rect = bx & 7;
    const int j    = bx >> 3;                    // 0..31 within rect
    const int n0   = (((rect >> 1) << 2) + (j >> 3)) << 7;
    const int m0   = (((rect & 1) << 3) + (j & 7)) << 7;
    const int tid  = threadIdx.x;
    const int wave = tid >> 6;
    const int lane = tid & 63;

    const _Float16* Ag = Qh  + ((size_t)b * N_ + n0) * D_;
    const _Float16* Bg = KTh + ((size_t)b * M_ + m0) * D_;

    // Stage 128x128 fp16 tiles with XOR swizzle on the GLOBAL address
    // (permutes 16B granules within each 256B row; LDS side stays linear).
    #pragma unroll
    for (int i = 0; i < 8; ++i) {
        const int chunk = wave * 8 + i;
        const int r     = chunk * 4 + (lane >> 4);
        const int g     = (lane & 15) ^ (r & 7);
        const int goff  = r * 128 + g * 8;
        __builtin_amdgcn_global_load_lds(
            (const __attribute__((address_space(1))) unsigned int*)(Ag + goff),
            (__attribute__((address_space(3))) unsigned int*)(&Ash[chunk * 512]), 16, 0, 0);
        __builtin_amdgcn_global_load_lds(
            (const __attribute__((address_space(1))) unsigned int*)(Bg + goff),
            (__attribute__((address_space(3))) unsigned int*)(&Bsh[chunk * 512]), 16, 0, 0);
    }
    __syncthreads();

    const int wr = (wave >> 1) * 64;
    const int wc = (wave & 1) * 64;
    const int lm = lane & 15;
    const int kq = lane >> 4;
    const int sw = lm & 7;

    f32x4 acc[4][4] = {};
    #pragma unroll
    for (int ks = 0; ks < 128; ks += 32) {
        const int gl = (ks >> 3) + kq;
        half8 af[4], bf[4];
        #pragma unroll
        for (int r = 0; r < 4; ++r)
            af[r] = *reinterpret_cast<const half8*>(
                &Ash[(wr + r * 16 + lm) * 128 + ((gl ^ sw) << 3)]);
        #pragma unroll
        for (int c = 0; c < 4; ++c)
            bf[c] = *reinterpret_cast<const half8*>(
                &Bsh[(wc + c * 16 + lm) * 128 + ((gl ^ sw) << 3)]);
        #pragma unroll
        for (int r = 0; r < 4; ++r)
            #pragma unroll
            for (int c = 0; c < 4; ++c)
                acc[r][c] = __builtin_amdgcn_mfma_f32_16x16x32_f16(af[r], bf[c], acc[r][c], 0, 0, 0);
    }

    // Epilogue: t = s*(qsq+ksq) - 2s*dot  (s pre-scaled by log2(e)); out = exp2(t).
    const float inv2s = -0.5f * __expf(-2.0f * ls[0]) * 1.4426950408889634f;
    const float cm2   = -2.0f * inv2s;
    const int l4 = (lane >> 4) * 4;
    const float* qsq = Qsq + (size_t)b * N_ + n0;
    const float* ksq = Ksq + (size_t)b * M_ + m0;

    float ksv[4];
    #pragma unroll
    for (int c = 0; c < 4; ++c) ksv[c] = ksq[wc + c * 16 + lm];
    float qsv[4][4];
    #pragma unroll
    for (int r = 0; r < 4; ++r)
        #pragma unroll
        for (int i = 0; i < 4; ++i) qsv[r][i] = qsq[wr + r * 16 + l4 + i];

    __syncthreads();
    float* Csh = (float*)smem;           // 128 rows x stride 132 f32

    #pragma unroll
    for (int r = 0; r < 4; ++r) {
        #pragma unroll
        for (int i = 0; i < 4; ++i) {
            const int row = wr + r * 16 + l4 + i;
            #pragma unroll
            for (int c = 0; c < 4; ++c) {
                const float t = fmaf(cm2, acc[r][c][i], inv2s * (qsv[r][i] + ksv[c]));
                Csh[row * 132 + wc + c * 16 + lm] = exp2f(t);
            }
        }
    }
    __syncthreads();

    // Linear readback: wave instr = 2 rows x 512B contiguous; non-temporal.
    float* Cb = out + ((size_t)b * N_ + n0) * (size_t)M_ + m0;
    const int trow = tid >> 5;
    const int tcol = (tid & 31) << 2;
    #pragma unroll
    for (int it = 0; it < 16; ++it) {
        const int row = it * 8 + trow;
        const f32x4 v = *reinterpret_cast<const f32x4*>(&Csh[row * 132 + tcol]);
        __builtin_nontemporal_store(v, reinterpret_cast<f32x4*>(&Cb[(size_t)row * M_ + tcol]));
    }
}

// ---------------------------------------------------------------- launch ----
extern "C" void kernel_launch(void* const* d_in, const int* in_sizes, int n_in,
                              void* d_out, int out_size, void* d_ws, size_t ws_size,
                              hipStream_t stream) {
    const float* Q  = (const float*)d_in[0];
    const float* KV = (const float*)d_in[1];
    const float* ls = (const float*)d_in[2];
    float* out = (float*)d_out;

    char* ws = (char*)d_ws;
    _Float16* Qh  = (_Float16*)ws;
    _Float16* KTh = (_Float16*)(ws + (size_t)8 * 1024 * 1024);
    float*    Qsq = (float*)(ws + (size_t)16 * 1024 * 1024);
    float*    Ksq = (float*)(ws + (size_t)16 * 1024 * 1024 + 128 * 1024);

    prep<<<dim3(8192 + 128), 256, 0, stream>>>(Q, KV, Qh, KTh, Qsq, Ksq);
    gauss_gemm<<<dim3(256, B_), 256, 0, stream>>>(Qh, KTh, Qsq, Ksq, ls, out);
}

// Round 4
// 321.708 us; speedup vs baseline: 1.0302x; 1.0302x over previous
//
#include <hip/hip_runtime.h>

// GaussianKernel: out[b,n,m] = exp(inv2s * (||Q[b,n]||^2 + ||KV[b,:,m]||^2 - 2*Q[b,n]·KV[b,:,m]))
// B=16, N=2048, M=2048, D=128, fp32 in/out.
//
// R4: revert R3's XCD swizzle (wrong dispatch-mapping assumption -> L2 thrash)
//     and NT stores. Keep merged prep (KV blocks FIRST to kill the tail) and
//     exp2f epilogue. Gemm is at its HBM write floor; window is fill-dominated.

#define B_  16
#define N_  2048
#define M_  2048
#define D_  128

typedef _Float16 half8 __attribute__((ext_vector_type(8)));
typedef float    f32x4 __attribute__((ext_vector_type(4)));

// ----------------------------------------------------------------- prep -----
// blocks [0, 128):    KV -> KTh[b,m,k] fp16 transpose + col-sq (long pole, first).
// blocks [128, 8320): Q rows -> fp16 + row-sq (one wave per row).
__global__ __launch_bounds__(256) void prep(const float* __restrict__ Q,
                                            const float* __restrict__ KV,
                                            _Float16* __restrict__ Qh,
                                            _Float16* __restrict__ KTh,
                                            float* __restrict__ Qsq,
                                            float* __restrict__ Ksq) {
    if (blockIdx.x < 128) {
        const int bid = blockIdx.x;                 // 0..127
        const int b   = bid >> 3;
        const int m   = (bid & 7) * 256 + threadIdx.x;
        const float* src = KV + (size_t)b * D_ * M_ + m;
        _Float16*   dst = KTh + ((size_t)b * M_ + m) * D_;
        float sq = 0.f;
        #pragma unroll 2
        for (int k0 = 0; k0 < D_; k0 += 8) {
            union { _Float16 h[8]; int4 v; } buf;
            #pragma unroll
            for (int j = 0; j < 8; ++j) {
                const float v = src[(size_t)(k0 + j) * M_];
                sq += v * v;
                buf.h[j] = (_Float16)v;
            }
            *reinterpret_cast<int4*>(dst + k0) = buf.v;
        }
        Ksq[(size_t)b * M_ + m] = sq;
    } else {
        const int row  = (blockIdx.x - 128) * 4 + (threadIdx.x >> 6);
        const int lane = threadIdx.x & 63;
        const float2 v = reinterpret_cast<const float2*>(Q + (size_t)row * D_)[lane];
        float sq = v.x * v.x + v.y * v.y;
        union { _Float16 h[2]; unsigned int u; } pk;
        pk.h[0] = (_Float16)v.x;
        pk.h[1] = (_Float16)v.y;
        reinterpret_cast<unsigned int*>(Qh + (size_t)row * D_)[lane] = pk.u;
        #pragma unroll
        for (int off = 32; off > 0; off >>= 1) sq += __shfl_down(sq, off, 64);
        if (lane == 0) Qsq[row] = sq;
    }
}

// ------------------------------------------------------------------ GEMM ----
// 128x128 tile per block, 4 waves (2x2 of 64x64), full K=128 staged once.
__global__ __launch_bounds__(256, 2) void gauss_gemm(
    const _Float16* __restrict__ Qh, const _Float16* __restrict__ KTh,
    const float* __restrict__ Qsq,  const float* __restrict__ Ksq,
    const float* __restrict__ ls,   float* __restrict__ out) {
    __shared__ __align__(16) char smem[132 * 128 * 4];   // 67584 B -> 2 blocks/CU
    _Float16* Ash = (_Float16*)smem;
    _Float16* Bsh = (_Float16*)(smem + 32768);

    const int b    = blockIdx.y;
    const int bx   = blockIdx.x;
    const int n0   = (bx >> 4) << 7;
    const int m0   = (bx & 15) << 7;
    const int tid  = threadIdx.x;
    const int wave = tid >> 6;
    const int lane = tid & 63;

    const _Float16* Ag = Qh  + ((size_t)b * N_ + n0) * D_;
    const _Float16* Bg = KTh + ((size_t)b * M_ + m0) * D_;

    // Stage 128x128 fp16 tiles with XOR swizzle on the GLOBAL address
    // (permutes 16B granules within each 256B row; LDS side stays linear).
    #pragma unroll
    for (int i = 0; i < 8; ++i) {
        const int chunk = wave * 8 + i;
        const int r     = chunk * 4 + (lane >> 4);
        const int g     = (lane & 15) ^ (r & 7);
        const int goff  = r * 128 + g * 8;
        __builtin_amdgcn_global_load_lds(
            (const __attribute__((address_space(1))) unsigned int*)(Ag + goff),
            (__attribute__((address_space(3))) unsigned int*)(&Ash[chunk * 512]), 16, 0, 0);
        __builtin_amdgcn_global_load_lds(
            (const __attribute__((address_space(1))) unsigned int*)(Bg + goff),
            (__attribute__((address_space(3))) unsigned int*)(&Bsh[chunk * 512]), 16, 0, 0);
    }
    __syncthreads();

    const int wr = (wave >> 1) * 64;
    const int wc = (wave & 1) * 64;
    const int lm = lane & 15;
    const int kq = lane >> 4;
    const int sw = lm & 7;

    f32x4 acc[4][4] = {};
    #pragma unroll
    for (int ks = 0; ks < 128; ks += 32) {
        const int gl = (ks >> 3) + kq;
        half8 af[4], bf[4];
        #pragma unroll
        for (int r = 0; r < 4; ++r)
            af[r] = *reinterpret_cast<const half8*>(
                &Ash[(wr + r * 16 + lm) * 128 + ((gl ^ sw) << 3)]);
        #pragma unroll
        for (int c = 0; c < 4; ++c)
            bf[c] = *reinterpret_cast<const half8*>(
                &Bsh[(wc + c * 16 + lm) * 128 + ((gl ^ sw) << 3)]);
        #pragma unroll
        for (int r = 0; r < 4; ++r)
            #pragma unroll
            for (int c = 0; c < 4; ++c)
                acc[r][c] = __builtin_amdgcn_mfma_f32_16x16x32_f16(af[r], bf[c], acc[r][c], 0, 0, 0);
    }

    // Epilogue: t = s*(qsq+ksq) - 2s*dot  (s pre-scaled by log2(e)); out = exp2(t).
    const float inv2s = -0.5f * __expf(-2.0f * ls[0]) * 1.4426950408889634f;
    const float cm2   = -2.0f * inv2s;
    const int l4 = (lane >> 4) * 4;
    const float* qsq = Qsq + (size_t)b * N_ + n0;
    const float* ksq = Ksq + (size_t)b * M_ + m0;

    float ksv[4];
    #pragma unroll
    for (int c = 0; c < 4; ++c) ksv[c] = ksq[wc + c * 16 + lm];
    float qsv[4][4];
    #pragma unroll
    for (int r = 0; r < 4; ++r)
        #pragma unroll
        for (int i = 0; i < 4; ++i) qsv[r][i] = qsq[wr + r * 16 + l4 + i];

    __syncthreads();
    float* Csh = (float*)smem;           // 128 rows x stride 132 f32

    #pragma unroll
    for (int r = 0; r < 4; ++r) {
        #pragma unroll
        for (int i = 0; i < 4; ++i) {
            const int row = wr + r * 16 + l4 + i;
            #pragma unroll
            for (int c = 0; c < 4; ++c) {
                const float t = fmaf(cm2, acc[r][c][i], inv2s * (qsv[r][i] + ksv[c]));
                Csh[row * 132 + wc + c * 16 + lm] = exp2f(t);
            }
        }
    }
    __syncthreads();

    // Linear readback: wave instr = 2 rows x 512B contiguous full-line stores.
    float* Cb = out + ((size_t)b * N_ + n0) * (size_t)M_ + m0;
    const int trow = tid >> 5;
    const int tcol = (tid & 31) << 2;
    #pragma unroll
    for (int it = 0; it < 16; ++it) {
        const int row = it * 8 + trow;
        const f32x4 v = *reinterpret_cast<const f32x4*>(&Csh[row * 132 + tcol]);
        *reinterpret_cast<f32x4*>(&Cb[(size_t)row * M_ + tcol]) = v;
    }
}

// ---------------------------------------------------------------- launch ----
extern "C" void kernel_launch(void* const* d_in, const int* in_sizes, int n_in,
                              void* d_out, int out_size, void* d_ws, size_t ws_size,
                              hipStream_t stream) {
    const float* Q  = (const float*)d_in[0];
    const float* KV = (const float*)d_in[1];
    const float* ls = (const float*)d_in[2];
    float* out = (float*)d_out;

    char* ws = (char*)d_ws;
    _Float16* Qh  = (_Float16*)ws;
    _Float16* KTh = (_Float16*)(ws + (size_t)8 * 1024 * 1024);
    float*    Qsq = (float*)(ws + (size_t)16 * 1024 * 1024);
    float*    Ksq = (float*)(ws + (size_t)16 * 1024 * 1024 + 128 * 1024);

    prep<<<dim3(8192 + 128), 256, 0, stream>>>(Q, KV, Qh, KTh, Qsq, Ksq);
    gauss_gemm<<<dim3(256, B_), 256, 0, stream>>>(Qh, KTh, Qsq, Ksq, ls, out);
}